// Round 8
// baseline (1838.097 us; speedup 1.0000x reference)
//
#include <hip/hip_runtime.h>

#define NNODES 100000
#define NEDGES 200000
#define NB     2048
#define DIM    256
#define NLAYERS 5
#define NSB    98      // ceil(100000/1024) scan blocks
#define MBLK   3125    // 100000 / 32 mlp blocks

typedef __bf16 bf16x8 __attribute__((ext_vector_type(8)));
typedef float  f32x4  __attribute__((ext_vector_type(4)));

__device__ __forceinline__ float bf2f(unsigned short u) {
    union { unsigned u; float f; } v; v.u = ((unsigned)u) << 16; return v.f;
}
__device__ __forceinline__ unsigned short f2bf(float f) {
    union { float f; unsigned u; } v; v.f = f;
    unsigned r = v.u + 0x7fff + ((v.u >> 16) & 1);   // RNE (finite values only)
    return (unsigned short)(r >> 16);
}

// z-storage abstraction (fp32 or bf16 depending on ws_size)
__device__ __forceinline__ float loadH(const float* p, size_t i) { return p[i]; }
__device__ __forceinline__ float loadH(const unsigned short* p, size_t i) { return bf2f(p[i]); }
__device__ __forceinline__ void storeH(float* p, size_t i, float v) { p[i] = v; }
__device__ __forceinline__ void storeH(unsigned short* p, size_t i, float v) { p[i] = f2bf(v); }
__device__ __forceinline__ float4 loadZ4(const float* z, size_t row, int ch) {
    return *(const float4*)&z[row * DIM + ch];
}
__device__ __forceinline__ float4 loadZ4(const unsigned short* z, size_t row, int ch) {
    ushort4 u = *(const ushort4*)&z[row * DIM + ch];
    float4 r; r.x = bf2f(u.x); r.y = bf2f(u.y); r.z = bf2f(u.z); r.w = bf2f(u.w); return r;
}

__global__ void zero_f32(float* __restrict__ p, int n) {
    int i = blockIdx.x * 256 + threadIdx.x;
    if (i < n) p[i] = 0.f;
}
__global__ void zero_i32(int* __restrict__ p, int n) {
    int i = blockIdx.x * 256 + threadIdx.x;
    if (i < n) p[i] = 0;
}

// ---- transpose+convert weights: W (L x K x Nw) fp32 -> Wt (L x Nw x K) bf16 ----
__global__ void transpose_w(const float* __restrict__ W,
                            unsigned short* __restrict__ Wt, int K, int Nw) {
    int l = blockIdx.y;
    int t = blockIdx.x * 256 + threadIdx.x;
    int total = K * Nw;
    if (t >= total) return;
    int k = t / Nw, n = t % Nw;
    Wt[(size_t)l * total + (size_t)n * K + k] = f2bf(W[(size_t)l * total + t]);
}

// ---- edge-embedding table: etab[l][bt*3+bd][d] = ee1[l][bt][d] + ee2[l][bd][d] ----
__global__ void build_etab(const float* __restrict__ ee1, const float* __restrict__ ee2,
                           float* __restrict__ etab) {
    int l = blockIdx.y, c = blockIdx.x, d = threadIdx.x;   // c in [0,15)
    etab[((size_t)l * 15 + c) * DIM + d] =
        ee1[((size_t)l * 5 + c / 3) * DIM + d] + ee2[((size_t)l * 3 + c % 3) * DIM + d];
}

// ---- h0 = x_emb1[x0] + x_emb2[x1] -> z ----
template <typename HT>
__global__ void node_init(const int* __restrict__ x,
                          const float* __restrict__ xe1,
                          const float* __restrict__ xe2,
                          HT* __restrict__ z) {
    int i = blockIdx.x, d = threadIdx.x;
    int i0 = x[2 * i], i1 = x[2 * i + 1];
    storeH(z, (size_t)i * DIM + d, xe1[i0 * DIM + d] + xe2[i1 * DIM + d]);
}

// ---- CSR build ----
__global__ void csr_hist(const int* __restrict__ ei, int* __restrict__ deg) {
    int j = blockIdx.x * 256 + threadIdx.x;
    if (j < NEDGES) atomicAdd(&deg[ei[NEDGES + j]], 1);
}
__global__ __launch_bounds__(1024) void scan_blk(const int* __restrict__ deg,
                                                 int* __restrict__ rowptr,
                                                 int* __restrict__ bsum) {
    __shared__ int s[1024];
    int b = blockIdx.x, t = threadIdx.x, i = b * 1024 + t;
    s[t] = (i < NNODES) ? deg[i] : 0;
    __syncthreads();
    #pragma unroll
    for (int off = 1; off < 1024; off <<= 1) {
        int u = (t >= off) ? s[t - off] : 0;
        __syncthreads();
        s[t] += u;
        __syncthreads();
    }
    if (i < NNODES) rowptr[i + 1] = s[t];
    if (t == 1023) bsum[b] = s[1023];
}
__global__ void scan_partials(int* __restrict__ bsum) {
    if (threadIdx.x == 0) {
        int acc = 0;
        for (int k = 0; k < NSB; ++k) { acc += bsum[k]; bsum[k] = acc; }
    }
}
__global__ void scan_add(int* __restrict__ rowptr, const int* __restrict__ bsum) {
    int b = blockIdx.x, t = threadIdx.x, i = b * 1024 + t;
    if (b > 0 && i < NNODES) rowptr[i + 1] += bsum[b - 1];
    if (b == 0 && t == 0) rowptr[0] = 0;
}
__global__ void csr_fill(const int* __restrict__ ei, const int* __restrict__ ea,
                         const int* __restrict__ rowptr, int* __restrict__ cur,
                         int* __restrict__ esrc, int* __restrict__ eattr) {
    int j = blockIdx.x * 256 + threadIdx.x;
    if (j >= NEDGES) return;
    int d = ei[NEDGES + j];
    int pos = atomicAdd(&cur[d], 1);
    int slot = rowptr[d] + pos;
    esrc[slot] = ei[j];
    eattr[slot] = ea[2 * j] * 3 + ea[2 * j + 1];
}

// ---- segment starts: start[g] = lower_bound(batch, g), g in [0, NB] ----
__global__ void seg_starts(const int* __restrict__ batch, int* __restrict__ start) {
    int g = blockIdx.x * 256 + threadIdx.x;
    if (g > NB) return;
    int lo = 0, hi = NNODES;
    while (lo < hi) { int mid = (lo + hi) >> 1; if (batch[mid] < g) lo = mid + 1; else hi = mid; }
    start[g] = lo;
}

// ---- gather: agg[i] = sum_in(h(src)+e) + h(i) + self_e, h(x)=applyBN? relu(z*a+c) : z ----
template <typename HT>
__global__ __launch_bounds__(256) void gather_csr(const HT* __restrict__ z,
                                                  const float* __restrict__ acv,
                                                  const float* __restrict__ etab_l,
                                                  const int* __restrict__ rowptr,
                                                  const int* __restrict__ esrc,
                                                  const int* __restrict__ eattr,
                                                  unsigned short* __restrict__ agg,
                                                  int applyBN) {
    int i = blockIdx.x * 4 + (threadIdx.x >> 6);
    int lane = threadIdx.x & 63, ch = lane * 4;
    float4 a4 = make_float4(1.f, 1.f, 1.f, 1.f), c4 = make_float4(0.f, 0.f, 0.f, 0.f);
    if (applyBN) { a4 = *(const float4*)&acv[ch]; c4 = *(const float4*)&acv[DIM + ch]; }

    float4 hv = loadZ4(z, (size_t)i, ch);
    if (applyBN) {
        hv.x = fmaxf(hv.x * a4.x + c4.x, 0.f); hv.y = fmaxf(hv.y * a4.y + c4.y, 0.f);
        hv.z = fmaxf(hv.z * a4.z + c4.z, 0.f); hv.w = fmaxf(hv.w * a4.w + c4.w, 0.f);
    }
    float4 se = *(const float4*)&etab_l[12 * DIM + ch];   // (bt=4,bd=0)
    float4 acc = make_float4(hv.x + se.x, hv.y + se.y, hv.z + se.z, hv.w + se.w);

    int r0 = rowptr[i], r1 = rowptr[i + 1];
    for (int e = r0; e < r1; ++e) {
        int s = esrc[e], cb = eattr[e];
        float4 h = loadZ4(z, (size_t)s, ch);
        if (applyBN) {
            h.x = fmaxf(h.x * a4.x + c4.x, 0.f); h.y = fmaxf(h.y * a4.y + c4.y, 0.f);
            h.z = fmaxf(h.z * a4.z + c4.z, 0.f); h.w = fmaxf(h.w * a4.w + c4.w, 0.f);
        }
        float4 ev = *(const float4*)&etab_l[cb * DIM + ch];
        acc.x += h.x + ev.x; acc.y += h.y + ev.y; acc.z += h.z + ev.z; acc.w += h.w + ev.w;
    }
    ushort4 o; o.x = f2bf(acc.x); o.y = f2bf(acc.y); o.z = f2bf(acc.z); o.w = f2bf(acc.w);
    *(ushort4*)&agg[(size_t)i * DIM + ch] = o;
}

// ---- fused MLP: z = relu(agg @ W1 + b1) @ W2 + b2, per-block col stats partials ----
// M=32 rows/block, 8 waves, 3125 blocks (no tail). Ts 33.3 KB -> 3 blocks/CU target.
template <typename HT>
__global__ __launch_bounds__(512, 6) void mlp32(const unsigned short* __restrict__ agg,
                                                const unsigned short* __restrict__ Wt1,
                                                const float* __restrict__ b1,
                                                const unsigned short* __restrict__ Wt2,
                                                const float* __restrict__ b2,
                                                HT* __restrict__ z,
                                                float* __restrict__ partial) {
    __shared__ unsigned short Ts[32 * 520];   // 33280 B; reused as z staging (row stride 1040 B)

    const int rowBase = blockIdx.x * 32;
    const int tid = threadIdx.x;
    const int lane = tid & 63, w = tid >> 6;
    const int lrow = lane & 15, lq = lane >> 4;

    // stage 1: t = relu(agg @ W1 + b1) -> Ts ; wave w owns t-cols [w*64, +64)
    {
        f32x4 acc[2][4]{};
        #pragma unroll
        for (int kk = 0; kk < DIM / 32; ++kk) {
            const int kc = kk * 32 + lq * 8;
            bf16x8 a[2], b[4];
            #pragma unroll
            for (int mi = 0; mi < 2; ++mi)
                a[mi] = *(const bf16x8*)&agg[(size_t)(rowBase + mi * 16 + lrow) * DIM + kc];
            #pragma unroll
            for (int ni = 0; ni < 4; ++ni)
                b[ni] = *(const bf16x8*)&Wt1[(size_t)(w * 64 + ni * 16 + lrow) * DIM + kc];
            #pragma unroll
            for (int mi = 0; mi < 2; ++mi)
                #pragma unroll
                for (int ni = 0; ni < 4; ++ni)
                    acc[mi][ni] = __builtin_amdgcn_mfma_f32_16x16x32_bf16(a[mi], b[ni], acc[mi][ni], 0, 0, 0);
        }
        #pragma unroll
        for (int ni = 0; ni < 4; ++ni) {
            int col = w * 64 + ni * 16 + lrow;
            float bv = b1[col];
            #pragma unroll
            for (int mi = 0; mi < 2; ++mi)
                #pragma unroll
                for (int r = 0; r < 4; ++r)
                    Ts[(mi * 16 + lq * 4 + r) * 520 + col] = f2bf(fmaxf(acc[mi][ni][r] + bv, 0.f));
        }
    }
    __syncthreads();

    // stage 2: acc2 = Ts @ W2 ; wave w owns z-cols [w*32, +32)
    f32x4 acc2[2][2]{};
    {
        #pragma unroll
        for (int kk = 0; kk < 2 * DIM / 32; ++kk) {
            const int kc = kk * 32 + lq * 8;
            bf16x8 a[2], b[2];
            #pragma unroll
            for (int mi = 0; mi < 2; ++mi)
                a[mi] = *(const bf16x8*)&Ts[(mi * 16 + lrow) * 520 + kc];
            #pragma unroll
            for (int ni = 0; ni < 2; ++ni)
                b[ni] = *(const bf16x8*)&Wt2[(size_t)(w * 32 + ni * 16 + lrow) * (2 * DIM) + kc];
            #pragma unroll
            for (int mi = 0; mi < 2; ++mi)
                #pragma unroll
                for (int ni = 0; ni < 2; ++ni)
                    acc2[mi][ni] = __builtin_amdgcn_mfma_f32_16x16x32_bf16(a[mi], b[ni], acc2[mi][ni], 0, 0, 0);
        }
    }
    __syncthreads();   // all waves done reading Ts; safe to overwrite

    // epilogue: stage z tile into LDS (row stride 1040 B) + per-block stats partials
    #pragma unroll
    for (int ni = 0; ni < 2; ++ni) {
        int col = w * 32 + ni * 16 + lrow;
        float bv = b2[col];
        float s = 0.f, q = 0.f;
        #pragma unroll
        for (int mi = 0; mi < 2; ++mi)
            #pragma unroll
            for (int r = 0; r < 4; ++r) {
                int rl = mi * 16 + lq * 4 + r;
                float v = acc2[mi][ni][r] + bv;
                ((HT*)((char*)Ts + (size_t)rl * 1040))[col] = (sizeof(HT) == 2) ? (HT)f2bf(v) : (HT)v;
                s += v; q += v * v;
            }
        s += __shfl_xor(s, 16); s += __shfl_xor(s, 32);
        q += __shfl_xor(q, 16); q += __shfl_xor(q, 32);
        if (lq == 0) {
            partial[(size_t)blockIdx.x * 512 + col] = s;
            partial[(size_t)blockIdx.x * 512 + 256 + col] = q;
        }
    }
    __syncthreads();

    // coalesced copy out: 16 B per lane
    {
        const int CH16 = (DIM * sizeof(HT)) / 16;   // 32 (bf16) or 64 (fp32) chunks/row
        for (int c = tid; c < 32 * CH16; c += 512) {
            int r = c / CH16, o = c % CH16;
            uint4 v = *(const uint4*)((const char*)Ts + (size_t)r * 1040 + o * 16);
            *(uint4*)((char*)z + (size_t)(rowBase + r) * DIM * sizeof(HT) + o * 16) = v;
        }
    }
}

// ---- stats[c] = sum_b partial[b*512 + c] ----
__global__ __launch_bounds__(512) void stats_reduce(const float* __restrict__ partial,
                                                    float* __restrict__ stats) {
    int c = threadIdx.x;
    float acc = 0.f;
    for (int b = blockIdx.x; b < MBLK; b += gridDim.x)
        acc += partial[(size_t)b * 512 + c];
    atomicAdd(&stats[c], acc);
}

__global__ void bn_finalize(const float* __restrict__ stats,
                            const float* __restrict__ g,
                            const float* __restrict__ b,
                            float* __restrict__ ac, int l) {
    int d = threadIdx.x;
    float mu = stats[d] / (float)NNODES;
    float var = stats[DIM + d] / (float)NNODES - mu * mu;
    float inv = rsqrtf(var + 1e-5f);
    float a = g[l * DIM + d] * inv;
    ac[d] = a;
    ac[DIM + d] = b[l * DIM + d] - mu * a;
}

// ---- pooled[g] = mean_i(relu(z[i]*a+c)) over sorted segment [start[g], start[g+1]) ----
template <typename HT>
__global__ __launch_bounds__(256) void pool_seg(const HT* __restrict__ z,
                                                const float* __restrict__ acv,
                                                const int* __restrict__ start,
                                                float* __restrict__ pooled) {
    int g = blockIdx.x, ch = threadIdx.x;
    int r0 = start[g], r1 = start[g + 1];
    float a = acv[ch], c = acv[DIM + ch];
    float s = 0.f;
    for (int i = r0; i < r1; ++i)
        s += fmaxf(loadH(z, (size_t)i * DIM + ch) * a + c, 0.f);
    float n = (float)(r1 - r0);
    pooled[(size_t)g * DIM + ch] = s / fmaxf(n, 1.f);
}

// ---- out = softplus(pooled @ Wo1 + bo1) @ Wo2 + bo2 (pooled pre-averaged), fp32 out ----
__global__ __launch_bounds__(128) void head_mlp(const float* __restrict__ pooled,
                                                const float* __restrict__ Wo1,
                                                const float* __restrict__ bo1,
                                                const float* __restrict__ Wo2,
                                                const float* __restrict__ bo2,
                                                float* __restrict__ out) {
    __shared__ float p[DIM];
    __shared__ float r0[128], r1[128];
    int g = blockIdx.x, j = threadIdx.x;
    for (int k = j; k < DIM; k += 128) p[k] = pooled[(size_t)g * DIM + k];
    __syncthreads();
    float acc = bo1[j];
    for (int k = 0; k < DIM; ++k) acc += p[k] * Wo1[k * 128 + j];
    float sp = (acc > 20.f) ? acc : log1pf(expf(acc));
    r0[j] = sp * Wo2[j * 2 + 0];
    r1[j] = sp * Wo2[j * 2 + 1];
    __syncthreads();
    for (int s = 64; s > 0; s >>= 1) {
        if (j < s) { r0[j] += r0[j + s]; r1[j] += r1[j + s]; }
        __syncthreads();
    }
    if (j == 0) {
        out[g * 2 + 0] = r0[0] + bo2[0];
        out[g * 2 + 1] = r1[0] + bo2[1];
    }
}

template <typename HT>
static void pipeline(void* const* d_in, float* out, char* ws, hipStream_t stream) {
    const int* x     = (const int*)d_in[0];
    const int* ei    = (const int*)d_in[1];
    const int* ea    = (const int*)d_in[2];
    const int* batch = (const int*)d_in[3];
    const float* xe1 = (const float*)d_in[4];
    const float* xe2 = (const float*)d_in[5];
    const float* ee1 = (const float*)d_in[6];
    const float* ee2 = (const float*)d_in[7];
    const float* W1  = (const float*)d_in[8];
    const float* b1  = (const float*)d_in[9];
    const float* W2  = (const float*)d_in[10];
    const float* b2  = (const float*)d_in[11];
    const float* bng = (const float*)d_in[12];
    const float* bnb = (const float*)d_in[13];
    const float* Wo1 = (const float*)d_in[14];
    const float* bo1 = (const float*)d_in[15];
    const float* Wo2 = (const float*)d_in[16];
    const float* bo2 = (const float*)d_in[17];

    size_t off = 0;
    auto alloc = [&](size_t bytes) { void* p = ws + off; off += (bytes + 255) & ~255ull; return p; };
    HT* z               = (HT*)alloc((size_t)NNODES * DIM * sizeof(HT));
    unsigned short* agg = (unsigned short*)alloc((size_t)NNODES * DIM * 2);
    unsigned short* Wt1 = (unsigned short*)alloc((size_t)NLAYERS * DIM * 2 * DIM * 2);
    unsigned short* Wt2 = (unsigned short*)alloc((size_t)NLAYERS * DIM * 2 * DIM * 2);
    float* partial      = (float*)alloc((size_t)MBLK * 512 * 4);
    float* etab         = (float*)alloc((size_t)NLAYERS * 15 * DIM * 4);
    float* stats        = (float*)alloc(2 * DIM * 4);
    float* ac           = (float*)alloc(2 * DIM * 4);
    float* pooled       = (float*)alloc((size_t)NB * DIM * 4);
    int* gstart         = (int*)alloc((size_t)(NB + 1) * 4);
    int* rowptr         = (int*)alloc((size_t)(NNODES + 1) * 4);
    int* deg            = (int*)alloc((size_t)NNODES * 4);     // also cursor
    int* esrc           = (int*)alloc((size_t)NEDGES * 4);
    int* eattr          = (int*)alloc((size_t)NEDGES * 4);
    int* bsum           = (int*)alloc((size_t)NSB * 4);

    const int WTOT = DIM * 2 * DIM;  // 131072

    // one-time prep
    transpose_w<<<dim3((WTOT + 255) / 256, NLAYERS), 256, 0, stream>>>(W1, Wt1, DIM, 2 * DIM);
    transpose_w<<<dim3((WTOT + 255) / 256, NLAYERS), 256, 0, stream>>>(W2, Wt2, 2 * DIM, DIM);
    build_etab<<<dim3(15, NLAYERS), DIM, 0, stream>>>(ee1, ee2, etab);
    node_init<HT><<<NNODES, DIM, 0, stream>>>(x, xe1, xe2, z);

    // CSR + segment build
    zero_i32<<<(NNODES + 255) / 256, 256, 0, stream>>>(deg, NNODES);
    csr_hist<<<(NEDGES + 255) / 256, 256, 0, stream>>>(ei, deg);
    scan_blk<<<NSB, 1024, 0, stream>>>(deg, rowptr, bsum);
    scan_partials<<<1, 64, 0, stream>>>(bsum);
    scan_add<<<NSB, 1024, 0, stream>>>(rowptr, bsum);
    zero_i32<<<(NNODES + 255) / 256, 256, 0, stream>>>(deg, NNODES);
    csr_fill<<<(NEDGES + 255) / 256, 256, 0, stream>>>(ei, ea, rowptr, deg, esrc, eattr);
    seg_starts<<<(NB + 1 + 255) / 256, 256, 0, stream>>>(batch, gstart);

    for (int l = 0; l < NLAYERS; ++l) {
        gather_csr<HT><<<NNODES / 4, 256, 0, stream>>>(z, ac, etab + (size_t)l * 15 * DIM,
                                                       rowptr, esrc, eattr, agg, l > 0 ? 1 : 0);
        mlp32<HT><<<MBLK, 512, 0, stream>>>(agg, Wt1 + (size_t)l * WTOT, b1 + l * 2 * DIM,
                                            Wt2 + (size_t)l * WTOT, b2 + l * DIM, z, partial);
        zero_f32<<<2, 256, 0, stream>>>(stats, 2 * DIM);
        stats_reduce<<<32, 512, 0, stream>>>(partial, stats);
        bn_finalize<<<1, DIM, 0, stream>>>(stats, bng, bnb, ac, l);
    }

    pool_seg<HT><<<NB, DIM, 0, stream>>>(z, ac, gstart, pooled);
    head_mlp<<<NB, 128, 0, stream>>>(pooled, Wo1, bo1, Wo2, bo2, out);
}

extern "C" void kernel_launch(void* const* d_in, const int* in_sizes, int n_in,
                              void* d_out, int out_size, void* d_ws, size_t ws_size,
                              hipStream_t stream) {
    (void)in_sizes; (void)n_in; (void)out_size;
    // layout A (z fp32): ~168 MB ; layout B (z bf16): ~117 MB
    const size_t NEED_A = 168000000ull;
    const size_t NEED_B = 117000000ull;
    if (ws_size >= NEED_A)
        pipeline<float>(d_in, (float*)d_out, (char*)d_ws, stream);
    else if (ws_size >= NEED_B)
        pipeline<unsigned short>(d_in, (float*)d_out, (char*)d_ws, stream);
    // else: insufficient scratch — launch nothing (visible absmax failure, no fault)
}

// Round 9
// 1307.578 us; speedup vs baseline: 1.4057x; 1.4057x over previous
//
#include <hip/hip_runtime.h>

#define NNODES 100000
#define NEDGES 200000
#define NB     2048
#define DIM    256
#define NLAYERS 5
#define NSB    98   // ceil(100000/1024) scan blocks

typedef __bf16 bf16x8 __attribute__((ext_vector_type(8)));
typedef float  f32x4  __attribute__((ext_vector_type(4)));

__device__ __forceinline__ float bf2f(unsigned short u) {
    union { unsigned u; float f; } v; v.u = ((unsigned)u) << 16; return v.f;
}
__device__ __forceinline__ unsigned short f2bf(float f) {
    union { float f; unsigned u; } v; v.f = f;
    unsigned r = v.u + 0x7fff + ((v.u >> 16) & 1);   // RNE (finite values only)
    return (unsigned short)(r >> 16);
}
__device__ __forceinline__ float4 loadZ4(const unsigned short* z, size_t row, int ch) {
    ushort4 u = *(const ushort4*)&z[row * DIM + ch];
    float4 r; r.x = bf2f(u.x); r.y = bf2f(u.y); r.z = bf2f(u.z); r.w = bf2f(u.w); return r;
}

__global__ void zero_i32(int* __restrict__ p, int n) {
    int i = blockIdx.x * 256 + threadIdx.x;
    if (i < n) p[i] = 0;
}

// ---- transpose+convert weights: W (L x K x Nw) fp32 -> Wt (L x Nw x K) bf16 ----
__global__ void transpose_w(const float* __restrict__ W,
                            unsigned short* __restrict__ Wt, int K, int Nw) {
    int l = blockIdx.y;
    int t = blockIdx.x * 256 + threadIdx.x;
    int total = K * Nw;
    if (t >= total) return;
    int k = t / Nw, n = t % Nw;
    Wt[(size_t)l * total + (size_t)n * K + k] = f2bf(W[(size_t)l * total + t]);
}

// ---- edge-embedding table ----
__global__ void build_etab(const float* __restrict__ ee1, const float* __restrict__ ee2,
                           float* __restrict__ etab) {
    int l = blockIdx.y, c = blockIdx.x, d = threadIdx.x;   // c in [0,15)
    etab[((size_t)l * 15 + c) * DIM + d] =
        ee1[((size_t)l * 5 + c / 3) * DIM + d] + ee2[((size_t)l * 3 + c % 3) * DIM + d];
}

// ---- CSR build ----
__global__ void csr_hist(const int* __restrict__ ei, int* __restrict__ deg) {
    int j = blockIdx.x * 256 + threadIdx.x;
    if (j < NEDGES) atomicAdd(&deg[ei[NEDGES + j]], 1);
}
__global__ __launch_bounds__(1024) void scan_blk(const int* __restrict__ deg,
                                                 int* __restrict__ rowptr,
                                                 int* __restrict__ bsum) {
    __shared__ int s[1024];
    int b = blockIdx.x, t = threadIdx.x, i = b * 1024 + t;
    s[t] = (i < NNODES) ? deg[i] : 0;
    __syncthreads();
    #pragma unroll
    for (int off = 1; off < 1024; off <<= 1) {
        int u = (t >= off) ? s[t - off] : 0;
        __syncthreads();
        s[t] += u;
        __syncthreads();
    }
    if (i < NNODES) rowptr[i + 1] = s[t];
    if (t == 1023) bsum[b] = s[1023];
}
__global__ void scan_partials(int* __restrict__ bsum) {
    if (threadIdx.x == 0) {
        int acc = 0;
        for (int k = 0; k < NSB; ++k) { acc += bsum[k]; bsum[k] = acc; }
    }
}
__global__ void scan_add(int* __restrict__ rowptr, const int* __restrict__ bsum) {
    int b = blockIdx.x, t = threadIdx.x, i = b * 1024 + t;
    if (b > 0 && i < NNODES) rowptr[i + 1] += bsum[b - 1];
    if (b == 0 && t == 0) rowptr[0] = 0;
}
// uses deg as its own cursor via atomicSub (no second zero pass)
__global__ void csr_fill(const int* __restrict__ ei, const int* __restrict__ ea,
                         const int* __restrict__ rowptr, int* __restrict__ deg,
                         int* __restrict__ esrc, int* __restrict__ eattr) {
    int j = blockIdx.x * 256 + threadIdx.x;
    if (j >= NEDGES) return;
    int d = ei[NEDGES + j];
    int pos = atomicSub(&deg[d], 1) - 1;
    int slot = rowptr[d] + pos;
    esrc[slot] = ei[j];
    eattr[slot] = ea[2 * j] * 3 + ea[2 * j + 1];
}

// ---- segment starts ----
__global__ void seg_starts(const int* __restrict__ batch, int* __restrict__ start) {
    int g = blockIdx.x * 256 + threadIdx.x;
    if (g > NB) return;
    int lo = 0, hi = NNODES;
    while (lo < hi) { int mid = (lo + hi) >> 1; if (batch[mid] < g) lo = mid + 1; else hi = mid; }
    start[g] = lo;
}

// ---- gather: agg[i] = sum_in(h(src)+e) + h(i) + self_e ----
// MODE 0: h = xe1[x0]+xe2[x1] (layer 0, node_init fused)
// MODE 1: h = relu(z*a+c), BN affine computed inline from prev stats
// Also zeroes statsZ (next layer's stats buffer) via block 0.
template <int MODE>
__global__ __launch_bounds__(256) void gather_k(const unsigned short* __restrict__ z,
                                                const int* __restrict__ x,
                                                const float* __restrict__ xe1,
                                                const float* __restrict__ xe2,
                                                const float* __restrict__ statsP,
                                                const float* __restrict__ g_,
                                                const float* __restrict__ b_,
                                                float* __restrict__ statsZ,
                                                const float* __restrict__ etab_l,
                                                const int* __restrict__ rowptr,
                                                const int* __restrict__ esrc,
                                                const int* __restrict__ eattr,
                                                unsigned short* __restrict__ agg) {
    if (blockIdx.x == 0) { statsZ[threadIdx.x] = 0.f; statsZ[256 + threadIdx.x] = 0.f; }
    int i = blockIdx.x * 4 + (threadIdx.x >> 6);
    int lane = threadIdx.x & 63, ch = lane * 4;

    float4 a4, c4;
    if (MODE == 1) {
        float4 s4 = *(const float4*)&statsP[ch];
        float4 q4 = *(const float4*)&statsP[256 + ch];
        float4 g4 = *(const float4*)&g_[ch];
        float4 b4 = *(const float4*)&b_[ch];
        const float invN = 1.0f / (float)NNODES;
        float mux = s4.x * invN, muy = s4.y * invN, muz = s4.z * invN, muw = s4.w * invN;
        a4.x = g4.x * rsqrtf(q4.x * invN - mux * mux + 1e-5f);
        a4.y = g4.y * rsqrtf(q4.y * invN - muy * muy + 1e-5f);
        a4.z = g4.z * rsqrtf(q4.z * invN - muz * muz + 1e-5f);
        a4.w = g4.w * rsqrtf(q4.w * invN - muw * muw + 1e-5f);
        c4.x = b4.x - mux * a4.x; c4.y = b4.y - muy * a4.y;
        c4.z = b4.z - muz * a4.z; c4.w = b4.w - muw * a4.w;
    }

    // h(row) inline
    auto hrow = [&](int row) -> float4 {
        if (MODE == 0) {
            int i0 = x[2 * row], i1 = x[2 * row + 1];
            float4 u = *(const float4*)&xe1[(size_t)i0 * DIM + ch];
            float4 v = *(const float4*)&xe2[(size_t)i1 * DIM + ch];
            return make_float4(u.x + v.x, u.y + v.y, u.z + v.z, u.w + v.w);
        } else {
            float4 h = loadZ4(z, (size_t)row, ch);
            h.x = fmaxf(h.x * a4.x + c4.x, 0.f); h.y = fmaxf(h.y * a4.y + c4.y, 0.f);
            h.z = fmaxf(h.z * a4.z + c4.z, 0.f); h.w = fmaxf(h.w * a4.w + c4.w, 0.f);
            return h;
        }
    };

    float4 se = *(const float4*)&etab_l[12 * DIM + ch];   // (bt=4,bd=0)
    float4 hv = hrow(i);
    float4 acc = make_float4(hv.x + se.x, hv.y + se.y, hv.z + se.z, hv.w + se.w);

    int r0 = rowptr[i], r1 = rowptr[i + 1];
    int e = r0;
    for (; e + 2 <= r1; e += 2) {   // pairwise: issue both loads before use (ILP)
        int s0 = esrc[e], c0 = eattr[e];
        int s1 = esrc[e + 1], c1 = eattr[e + 1];
        float4 h0 = hrow(s0);
        float4 h1 = hrow(s1);
        float4 e0 = *(const float4*)&etab_l[c0 * DIM + ch];
        float4 e1 = *(const float4*)&etab_l[c1 * DIM + ch];
        acc.x += h0.x + e0.x + h1.x + e1.x; acc.y += h0.y + e0.y + h1.y + e1.y;
        acc.z += h0.z + e0.z + h1.z + e1.z; acc.w += h0.w + e0.w + h1.w + e1.w;
    }
    if (e < r1) {
        int s0 = esrc[e], c0 = eattr[e];
        float4 h0 = hrow(s0);
        float4 e0 = *(const float4*)&etab_l[c0 * DIM + ch];
        acc.x += h0.x + e0.x; acc.y += h0.y + e0.y;
        acc.z += h0.z + e0.z; acc.w += h0.w + e0.w;
    }
    ushort4 o; o.x = f2bf(acc.x); o.y = f2bf(acc.y); o.z = f2bf(acc.z); o.w = f2bf(acc.w);
    *(ushort4*)&agg[(size_t)i * DIM + ch] = o;
}

// ---- fused MLP (round-6 body): z = relu(agg @ W1 + b1) @ W2 + b2 + stats atomics ----
__global__ __launch_bounds__(512, 4) void mlp64(const unsigned short* __restrict__ agg,
                                                const unsigned short* __restrict__ Wt1,
                                                const float* __restrict__ b1,
                                                const unsigned short* __restrict__ Wt2,
                                                const float* __restrict__ b2,
                                                unsigned short* __restrict__ z,
                                                float* __restrict__ stats) {
    __shared__ unsigned short Ts[64 * 520];   // 66.6 KB

    const int rowBase = blockIdx.x * 64;
    const int tid = threadIdx.x;
    const int lane = tid & 63, w = tid >> 6;
    const int lrow = lane & 15, lq = lane >> 4;

    // stage 1: t = relu(agg @ W1 + b1) -> Ts
    {
        f32x4 acc[4][4]{};
        #pragma unroll
        for (int kk = 0; kk < DIM / 32; ++kk) {
            const int kc = kk * 32 + lq * 8;
            bf16x8 a[4], b[4];
            #pragma unroll
            for (int mi = 0; mi < 4; ++mi) {
                int row = rowBase + mi * 16 + lrow; if (row >= NNODES) row = NNODES - 1;
                a[mi] = *(const bf16x8*)&agg[(size_t)row * DIM + kc];
            }
            #pragma unroll
            for (int ni = 0; ni < 4; ++ni)
                b[ni] = *(const bf16x8*)&Wt1[(size_t)(w * 64 + ni * 16 + lrow) * DIM + kc];
            #pragma unroll
            for (int mi = 0; mi < 4; ++mi)
                #pragma unroll
                for (int ni = 0; ni < 4; ++ni)
                    acc[mi][ni] = __builtin_amdgcn_mfma_f32_16x16x32_bf16(a[mi], b[ni], acc[mi][ni], 0, 0, 0);
        }
        #pragma unroll
        for (int ni = 0; ni < 4; ++ni) {
            int col = w * 64 + ni * 16 + lrow;
            float bv = b1[col];
            #pragma unroll
            for (int mi = 0; mi < 4; ++mi)
                #pragma unroll
                for (int r = 0; r < 4; ++r)
                    Ts[(mi * 16 + lq * 4 + r) * 520 + col] = f2bf(fmaxf(acc[mi][ni][r] + bv, 0.f));
        }
    }
    __syncthreads();

    // stage 2: z = Ts @ W2 + b2 ; stats atomics
    {
        f32x4 acc[4][2]{};
        #pragma unroll
        for (int kk = 0; kk < 2 * DIM / 32; ++kk) {
            const int kc = kk * 32 + lq * 8;
            bf16x8 a[4], b[2];
            #pragma unroll
            for (int mi = 0; mi < 4; ++mi)
                a[mi] = *(const bf16x8*)&Ts[(mi * 16 + lrow) * 520 + kc];
            #pragma unroll
            for (int ni = 0; ni < 2; ++ni)
                b[ni] = *(const bf16x8*)&Wt2[(size_t)(w * 32 + ni * 16 + lrow) * (2 * DIM) + kc];
            #pragma unroll
            for (int mi = 0; mi < 4; ++mi)
                #pragma unroll
                for (int ni = 0; ni < 2; ++ni)
                    acc[mi][ni] = __builtin_amdgcn_mfma_f32_16x16x32_bf16(a[mi], b[ni], acc[mi][ni], 0, 0, 0);
        }
        #pragma unroll
        for (int ni = 0; ni < 2; ++ni) {
            int col = w * 32 + ni * 16 + lrow;
            float bv = b2[col];
            float s = 0.f, q = 0.f;
            #pragma unroll
            for (int mi = 0; mi < 4; ++mi)
                #pragma unroll
                for (int r = 0; r < 4; ++r) {
                    int row = rowBase + mi * 16 + lq * 4 + r;
                    if (row < NNODES) {
                        float v = acc[mi][ni][r] + bv;
                        z[(size_t)row * DIM + col] = f2bf(v);
                        s += v; q += v * v;
                    }
                }
            s += __shfl_xor(s, 16); s += __shfl_xor(s, 32);
            q += __shfl_xor(q, 16); q += __shfl_xor(q, 32);
            if (lq == 0) {
                atomicAdd(&stats[col], s);
                atomicAdd(&stats[DIM + col], q);
            }
        }
    }
}

// ---- pooled[g] = mean(relu(z*a+c)) over sorted segment; BN inline from stats ----
__global__ __launch_bounds__(256) void pool_seg(const unsigned short* __restrict__ z,
                                                const float* __restrict__ statsP,
                                                const float* __restrict__ g_,
                                                const float* __restrict__ b_,
                                                const int* __restrict__ start,
                                                float* __restrict__ pooled) {
    int g = blockIdx.x, ch = threadIdx.x;
    float mu = statsP[ch] / (float)NNODES;
    float var = statsP[256 + ch] / (float)NNODES - mu * mu;
    float a = g_[ch] * rsqrtf(var + 1e-5f);
    float c = b_[ch] - mu * a;
    int r0 = start[g], r1 = start[g + 1];
    float s = 0.f;
    for (int i = r0; i < r1; ++i)
        s += fmaxf(bf2f(z[(size_t)i * DIM + ch]) * a + c, 0.f);
    pooled[(size_t)g * DIM + ch] = s / fmaxf((float)(r1 - r0), 1.f);
}

// ---- head MLP ----
__global__ __launch_bounds__(128) void head_mlp(const float* __restrict__ pooled,
                                                const float* __restrict__ Wo1,
                                                const float* __restrict__ bo1,
                                                const float* __restrict__ Wo2,
                                                const float* __restrict__ bo2,
                                                float* __restrict__ out) {
    __shared__ float p[DIM];
    __shared__ float r0[128], r1[128];
    int g = blockIdx.x, j = threadIdx.x;
    for (int k = j; k < DIM; k += 128) p[k] = pooled[(size_t)g * DIM + k];
    __syncthreads();
    float acc = bo1[j];
    for (int k = 0; k < DIM; ++k) acc += p[k] * Wo1[k * 128 + j];
    float sp = (acc > 20.f) ? acc : log1pf(expf(acc));
    r0[j] = sp * Wo2[j * 2 + 0];
    r1[j] = sp * Wo2[j * 2 + 1];
    __syncthreads();
    for (int s = 64; s > 0; s >>= 1) {
        if (j < s) { r0[j] += r0[j + s]; r1[j] += r1[j + s]; }
        __syncthreads();
    }
    if (j == 0) {
        out[g * 2 + 0] = r0[0] + bo2[0];
        out[g * 2 + 1] = r1[0] + bo2[1];
    }
}

extern "C" void kernel_launch(void* const* d_in, const int* in_sizes, int n_in,
                              void* d_out, int out_size, void* d_ws, size_t ws_size,
                              hipStream_t stream) {
    (void)in_sizes; (void)n_in; (void)out_size;
    const int* x     = (const int*)d_in[0];
    const int* ei    = (const int*)d_in[1];
    const int* ea    = (const int*)d_in[2];
    const int* batch = (const int*)d_in[3];
    const float* xe1 = (const float*)d_in[4];
    const float* xe2 = (const float*)d_in[5];
    const float* ee1 = (const float*)d_in[6];
    const float* ee2 = (const float*)d_in[7];
    const float* W1  = (const float*)d_in[8];
    const float* b1  = (const float*)d_in[9];
    const float* W2  = (const float*)d_in[10];
    const float* b2  = (const float*)d_in[11];
    const float* bng = (const float*)d_in[12];
    const float* bnb = (const float*)d_in[13];
    const float* Wo1 = (const float*)d_in[14];
    const float* bo1 = (const float*)d_in[15];
    const float* Wo2 = (const float*)d_in[16];
    const float* bo2 = (const float*)d_in[17];
    float* out = (float*)d_out;

    if (ws_size < 112000000ull) return;   // need ~110 MB

    char* ws = (char*)d_ws;
    size_t off = 0;
    auto alloc = [&](size_t bytes) { void* p = ws + off; off += (bytes + 255) & ~255ull; return p; };
    unsigned short* z   = (unsigned short*)alloc((size_t)NNODES * DIM * 2);
    unsigned short* agg = (unsigned short*)alloc((size_t)NNODES * DIM * 2);
    unsigned short* Wt1 = (unsigned short*)alloc((size_t)NLAYERS * DIM * 2 * DIM * 2);
    unsigned short* Wt2 = (unsigned short*)alloc((size_t)NLAYERS * DIM * 2 * DIM * 2);
    float* etab         = (float*)alloc((size_t)NLAYERS * 15 * DIM * 4);
    float* stats        = (float*)alloc(2 * 512 * 4);          // ping-pong [2][512]
    float* pooled       = (float*)alloc((size_t)NB * DIM * 4);
    int* gstart         = (int*)alloc((size_t)(NB + 1) * 4);
    int* rowptr         = (int*)alloc((size_t)(NNODES + 1) * 4);
    int* deg            = (int*)alloc((size_t)NNODES * 4);
    int* esrc           = (int*)alloc((size_t)NEDGES * 4);
    int* eattr          = (int*)alloc((size_t)NEDGES * 4);
    int* bsum           = (int*)alloc((size_t)NSB * 4);

    const int WTOT = DIM * 2 * DIM;  // 131072

    transpose_w<<<dim3((WTOT + 255) / 256, NLAYERS), 256, 0, stream>>>(W1, Wt1, DIM, 2 * DIM);
    transpose_w<<<dim3((WTOT + 255) / 256, NLAYERS), 256, 0, stream>>>(W2, Wt2, 2 * DIM, DIM);
    build_etab<<<dim3(15, NLAYERS), DIM, 0, stream>>>(ee1, ee2, etab);

    zero_i32<<<(NNODES + 255) / 256, 256, 0, stream>>>(deg, NNODES);
    csr_hist<<<(NEDGES + 255) / 256, 256, 0, stream>>>(ei, deg);
    scan_blk<<<NSB, 1024, 0, stream>>>(deg, rowptr, bsum);
    scan_partials<<<1, 64, 0, stream>>>(bsum);
    scan_add<<<NSB, 1024, 0, stream>>>(rowptr, bsum);
    csr_fill<<<(NEDGES + 255) / 256, 256, 0, stream>>>(ei, ea, rowptr, deg, esrc, eattr);
    seg_starts<<<(NB + 1 + 255) / 256, 256, 0, stream>>>(batch, gstart);

    for (int l = 0; l < NLAYERS; ++l) {
        float* statsP = stats + ((l + 1) & 1) * 512;   // prev layer's stats
        float* statsC = stats + (l & 1) * 512;         // this layer's stats (zeroed by gather)
        if (l == 0)
            gather_k<0><<<NNODES / 4, 256, 0, stream>>>(z, x, xe1, xe2, statsP, bng, bnb, statsC,
                                                        etab, rowptr, esrc, eattr, agg);
        else
            gather_k<1><<<NNODES / 4, 256, 0, stream>>>(z, x, xe1, xe2, statsP,
                                                        bng + (size_t)(l - 1) * DIM, bnb + (size_t)(l - 1) * DIM,
                                                        statsC, etab + (size_t)l * 15 * DIM,
                                                        rowptr, esrc, eattr, agg);
        mlp64<<<(NNODES + 63) / 64, 512, 0, stream>>>(agg, Wt1 + (size_t)l * WTOT, b1 + l * 2 * DIM,
                                                      Wt2 + (size_t)l * WTOT, b2 + l * DIM, z, statsC);
    }

    pool_seg<<<NB, DIM, 0, stream>>>(z, stats + ((NLAYERS - 1) & 1) * 512,
                                     bng + (size_t)(NLAYERS - 1) * DIM, bnb + (size_t)(NLAYERS - 1) * DIM,
                                     gstart, pooled);
    head_mlp<<<NB, 128, 0, stream>>>(pooled, Wo1, bo1, Wo2, bo2, out);
}

// Round 10
// 1100.820 us; speedup vs baseline: 1.6698x; 1.1878x over previous
//
#include <hip/hip_runtime.h>

#define NNODES 100000
#define NEDGES 200000
#define NB     2048
#define DIM    256
#define NLAYERS 5
#define NSB    98   // ceil(100000/1024) scan blocks

typedef __bf16 bf16x8 __attribute__((ext_vector_type(8)));
typedef float  f32x4  __attribute__((ext_vector_type(4)));

__device__ __forceinline__ float bf2f(unsigned short u) {
    union { unsigned u; float f; } v; v.u = ((unsigned)u) << 16; return v.f;
}
__device__ __forceinline__ unsigned short f2bf(float f) {
    union { float f; unsigned u; } v; v.f = f;
    unsigned r = v.u + 0x7fff + ((v.u >> 16) & 1);   // RNE (finite values only)
    return (unsigned short)(r >> 16);
}
__device__ __forceinline__ float4 loadZ4(const unsigned short* z, size_t row, int ch) {
    ushort4 u = *(const ushort4*)&z[row * DIM + ch];
    float4 r; r.x = bf2f(u.x); r.y = bf2f(u.y); r.z = bf2f(u.z); r.w = bf2f(u.w); return r;
}

__global__ void zero_i32(int* __restrict__ p, int n) {
    int i = blockIdx.x * 256 + threadIdx.x;
    if (i < n) p[i] = 0;
}

// ---- transpose+convert weights: W (L x K x Nw) fp32 -> Wt (L x Nw x K) bf16 ----
__global__ void transpose_w(const float* __restrict__ W,
                            unsigned short* __restrict__ Wt, int K, int Nw) {
    int l = blockIdx.y;
    int t = blockIdx.x * 256 + threadIdx.x;
    int total = K * Nw;
    if (t >= total) return;
    int k = t / Nw, n = t % Nw;
    Wt[(size_t)l * total + (size_t)n * K + k] = f2bf(W[(size_t)l * total + t]);
}

// ---- edge-embedding table ----
__global__ void build_etab(const float* __restrict__ ee1, const float* __restrict__ ee2,
                           float* __restrict__ etab) {
    int l = blockIdx.y, c = blockIdx.x, d = threadIdx.x;   // c in [0,15)
    etab[((size_t)l * 15 + c) * DIM + d] =
        ee1[((size_t)l * 5 + c / 3) * DIM + d] + ee2[((size_t)l * 3 + c % 3) * DIM + d];
}

// ---- CSR build ----
__global__ void csr_hist(const int* __restrict__ ei, int* __restrict__ deg) {
    int j = blockIdx.x * 256 + threadIdx.x;
    if (j < NEDGES) atomicAdd(&deg[ei[NEDGES + j]], 1);
}
__global__ __launch_bounds__(1024) void scan_blk(const int* __restrict__ deg,
                                                 int* __restrict__ rowptr,
                                                 int* __restrict__ bsum) {
    __shared__ int s[1024];
    int b = blockIdx.x, t = threadIdx.x, i = b * 1024 + t;
    s[t] = (i < NNODES) ? deg[i] : 0;
    __syncthreads();
    #pragma unroll
    for (int off = 1; off < 1024; off <<= 1) {
        int u = (t >= off) ? s[t - off] : 0;
        __syncthreads();
        s[t] += u;
        __syncthreads();
    }
    if (i < NNODES) rowptr[i + 1] = s[t];
    if (t == 1023) bsum[b] = s[1023];
}
__global__ void scan_partials(int* __restrict__ bsum) {
    if (threadIdx.x == 0) {
        int acc = 0;
        for (int k = 0; k < NSB; ++k) { acc += bsum[k]; bsum[k] = acc; }
    }
}
__global__ void scan_add(int* __restrict__ rowptr, const int* __restrict__ bsum) {
    int b = blockIdx.x, t = threadIdx.x, i = b * 1024 + t;
    if (b > 0 && i < NNODES) rowptr[i + 1] += bsum[b - 1];
    if (b == 0 && t == 0) rowptr[0] = 0;
}
// uses deg as its own cursor via atomicSub (no second zero pass)
__global__ void csr_fill(const int* __restrict__ ei, const int* __restrict__ ea,
                         const int* __restrict__ rowptr, int* __restrict__ deg,
                         int* __restrict__ esrc, int* __restrict__ eattr) {
    int j = blockIdx.x * 256 + threadIdx.x;
    if (j >= NEDGES) return;
    int d = ei[NEDGES + j];
    int pos = atomicSub(&deg[d], 1) - 1;
    int slot = rowptr[d] + pos;
    esrc[slot] = ei[j];
    eattr[slot] = ea[2 * j] * 3 + ea[2 * j + 1];
}

// ---- segment starts ----
__global__ void seg_starts(const int* __restrict__ batch, int* __restrict__ start) {
    int g = blockIdx.x * 256 + threadIdx.x;
    if (g > NB) return;
    int lo = 0, hi = NNODES;
    while (lo < hi) { int mid = (lo + hi) >> 1; if (batch[mid] < g) lo = mid + 1; else hi = mid; }
    start[g] = lo;
}

// ---- gather: agg[i] = sum_in(h(src)+e) + h(i) + self_e ----
template <int MODE>
__global__ __launch_bounds__(256) void gather_k(const unsigned short* __restrict__ z,
                                                const int* __restrict__ x,
                                                const float* __restrict__ xe1,
                                                const float* __restrict__ xe2,
                                                const float* __restrict__ statsP,
                                                const float* __restrict__ g_,
                                                const float* __restrict__ b_,
                                                float* __restrict__ statsZ,
                                                const float* __restrict__ etab_l,
                                                const int* __restrict__ rowptr,
                                                const int* __restrict__ esrc,
                                                const int* __restrict__ eattr,
                                                unsigned short* __restrict__ agg) {
    if (blockIdx.x == 0) { statsZ[threadIdx.x] = 0.f; statsZ[256 + threadIdx.x] = 0.f; }
    int i = blockIdx.x * 4 + (threadIdx.x >> 6);
    int lane = threadIdx.x & 63, ch = lane * 4;

    float4 a4, c4;
    if (MODE == 1) {
        float4 s4 = *(const float4*)&statsP[ch];
        float4 q4 = *(const float4*)&statsP[256 + ch];
        float4 g4 = *(const float4*)&g_[ch];
        float4 b4 = *(const float4*)&b_[ch];
        const float invN = 1.0f / (float)NNODES;
        float mux = s4.x * invN, muy = s4.y * invN, muz = s4.z * invN, muw = s4.w * invN;
        a4.x = g4.x * rsqrtf(q4.x * invN - mux * mux + 1e-5f);
        a4.y = g4.y * rsqrtf(q4.y * invN - muy * muy + 1e-5f);
        a4.z = g4.z * rsqrtf(q4.z * invN - muz * muz + 1e-5f);
        a4.w = g4.w * rsqrtf(q4.w * invN - muw * muw + 1e-5f);
        c4.x = b4.x - mux * a4.x; c4.y = b4.y - muy * a4.y;
        c4.z = b4.z - muz * a4.z; c4.w = b4.w - muw * a4.w;
    }

    auto hrow = [&](int row) -> float4 {
        if (MODE == 0) {
            int i0 = x[2 * row], i1 = x[2 * row + 1];
            float4 u = *(const float4*)&xe1[(size_t)i0 * DIM + ch];
            float4 v = *(const float4*)&xe2[(size_t)i1 * DIM + ch];
            return make_float4(u.x + v.x, u.y + v.y, u.z + v.z, u.w + v.w);
        } else {
            float4 h = loadZ4(z, (size_t)row, ch);
            h.x = fmaxf(h.x * a4.x + c4.x, 0.f); h.y = fmaxf(h.y * a4.y + c4.y, 0.f);
            h.z = fmaxf(h.z * a4.z + c4.z, 0.f); h.w = fmaxf(h.w * a4.w + c4.w, 0.f);
            return h;
        }
    };

    float4 se = *(const float4*)&etab_l[12 * DIM + ch];   // (bt=4,bd=0)
    float4 hv = hrow(i);
    float4 acc = make_float4(hv.x + se.x, hv.y + se.y, hv.z + se.z, hv.w + se.w);

    int r0 = rowptr[i], r1 = rowptr[i + 1];
    int e = r0;
    for (; e + 2 <= r1; e += 2) {
        int s0 = esrc[e], c0 = eattr[e];
        int s1 = esrc[e + 1], c1 = eattr[e + 1];
        float4 h0 = hrow(s0);
        float4 h1 = hrow(s1);
        float4 e0 = *(const float4*)&etab_l[c0 * DIM + ch];
        float4 e1 = *(const float4*)&etab_l[c1 * DIM + ch];
        acc.x += h0.x + e0.x + h1.x + e1.x; acc.y += h0.y + e0.y + h1.y + e1.y;
        acc.z += h0.z + e0.z + h1.z + e1.z; acc.w += h0.w + e0.w + h1.w + e1.w;
    }
    if (e < r1) {
        int s0 = esrc[e], c0 = eattr[e];
        float4 h0 = hrow(s0);
        float4 e0 = *(const float4*)&etab_l[c0 * DIM + ch];
        acc.x += h0.x + e0.x; acc.y += h0.y + e0.y;
        acc.z += h0.z + e0.z; acc.w += h0.w + e0.w;
    }
    ushort4 o; o.x = f2bf(acc.x); o.y = f2bf(acc.y); o.z = f2bf(acc.z); o.w = f2bf(acc.w);
    *(ushort4*)&agg[(size_t)i * DIM + ch] = o;
}

// ---- fused MLP, quarter-split: As in LDS once; t processed in 4 column-quarters ----
// LDS = As 33.8 KB + Ts 17.4 KB = 50 KB -> 3 blocks/CU target (launch_bounds 512,6).
// acc2 (z-cols) persistent across quarters; stage-1(q) overlaps stage-2(q-1) drain.
__global__ __launch_bounds__(512, 6) void mlp64(const unsigned short* __restrict__ agg,
                                                const unsigned short* __restrict__ Wt1,
                                                const float* __restrict__ b1,
                                                const unsigned short* __restrict__ Wt2,
                                                const float* __restrict__ b2,
                                                unsigned short* __restrict__ z,
                                                float* __restrict__ stats) {
    __shared__ unsigned short As[64 * 264];   // 33792 B
    __shared__ unsigned short Ts[64 * 136];   // 17408 B (one t-quarter: 128 cols + 8 pad)

    const int rowBase = blockIdx.x * 64;
    const int tid = threadIdx.x;
    const int lane = tid & 63, w = tid >> 6;
    const int lrow = lane & 15, lq = lane >> 4;

    // stage A: 64x256 bf16 tile -> LDS (16 B per thread x 4)
    #pragma unroll
    for (int c = tid; c < 64 * 32; c += 512) {
        int r = c >> 5, cc = c & 31;
        int row = rowBase + r; if (row >= NNODES) row = NNODES - 1;
        *(uint4*)&As[r * 264 + cc * 8] = *(const uint4*)&agg[(size_t)row * DIM + cc * 8];
    }
    f32x4 acc2[4][2]{};
    __syncthreads();

    #pragma unroll
    for (int q = 0; q < 4; ++q) {
        // stage 1: t-quarter cols q*128 + w*16 + [0,16); K=256 from As
        f32x4 acc1[4]{};
        const unsigned short* w1p = &Wt1[(size_t)(q * 128 + w * 16 + lrow) * DIM];
        #pragma unroll
        for (int kk = 0; kk < 8; ++kk) {
            const int kc = kk * 32 + lq * 8;
            bf16x8 b = *(const bf16x8*)&w1p[kc];
            bf16x8 a[4];
            #pragma unroll
            for (int mi = 0; mi < 4; ++mi)
                a[mi] = *(const bf16x8*)&As[(mi * 16 + lrow) * 264 + kc];
            #pragma unroll
            for (int mi = 0; mi < 4; ++mi)
                acc1[mi] = __builtin_amdgcn_mfma_f32_16x16x32_bf16(a[mi], b, acc1[mi], 0, 0, 0);
        }
        if (q > 0) __syncthreads();   // prev quarter's stage-2 reads of Ts complete
        {
            int col = w * 16 + lrow;
            float bv = b1[q * 128 + col];
            #pragma unroll
            for (int mi = 0; mi < 4; ++mi)
                #pragma unroll
                for (int r = 0; r < 4; ++r)
                    Ts[(mi * 16 + lq * 4 + r) * 136 + col] = f2bf(fmaxf(acc1[mi][r] + bv, 0.f));
        }
        __syncthreads();
        // stage 2: acc2 += Ts(64x128) @ W2[k-slice q*128..]; wave w -> z-cols w*32+[0,32)
        #pragma unroll
        for (int kk = 0; kk < 4; ++kk) {
            const int kc = kk * 32 + lq * 8;
            bf16x8 a[4], b[2];
            #pragma unroll
            for (int mi = 0; mi < 4; ++mi)
                a[mi] = *(const bf16x8*)&Ts[(mi * 16 + lrow) * 136 + kc];
            #pragma unroll
            for (int ni = 0; ni < 2; ++ni)
                b[ni] = *(const bf16x8*)&Wt2[(size_t)(w * 32 + ni * 16 + lrow) * (2 * DIM) + q * 128 + kc];
            #pragma unroll
            for (int mi = 0; mi < 4; ++mi)
                #pragma unroll
                for (int ni = 0; ni < 2; ++ni)
                    acc2[mi][ni] = __builtin_amdgcn_mfma_f32_16x16x32_bf16(a[mi], b[ni], acc2[mi][ni], 0, 0, 0);
        }
    }

    // epilogue: z store + stats atomics (r9 form)
    #pragma unroll
    for (int ni = 0; ni < 2; ++ni) {
        int col = w * 32 + ni * 16 + lrow;
        float bv = b2[col];
        float s = 0.f, q = 0.f;
        #pragma unroll
        for (int mi = 0; mi < 4; ++mi)
            #pragma unroll
            for (int r = 0; r < 4; ++r) {
                int row = rowBase + mi * 16 + lq * 4 + r;
                if (row < NNODES) {
                    float v = acc2[mi][ni][r] + bv;
                    z[(size_t)row * DIM + col] = f2bf(v);
                    s += v; q += v * v;
                }
            }
        s += __shfl_xor(s, 16); s += __shfl_xor(s, 32);
        q += __shfl_xor(q, 16); q += __shfl_xor(q, 32);
        if (lq == 0) {
            atomicAdd(&stats[col], s);
            atomicAdd(&stats[DIM + col], q);
        }
    }
}

// ---- pooled[g] = mean(relu(z*a+c)) over sorted segment; BN inline from stats ----
__global__ __launch_bounds__(256) void pool_seg(const unsigned short* __restrict__ z,
                                                const float* __restrict__ statsP,
                                                const float* __restrict__ g_,
                                                const float* __restrict__ b_,
                                                const int* __restrict__ start,
                                                float* __restrict__ pooled) {
    int g = blockIdx.x, ch = threadIdx.x;
    float mu = statsP[ch] / (float)NNODES;
    float var = statsP[256 + ch] / (float)NNODES - mu * mu;
    float a = g_[ch] * rsqrtf(var + 1e-5f);
    float c = b_[ch] - mu * a;
    int r0 = start[g], r1 = start[g + 1];
    float s = 0.f;
    for (int i = r0; i < r1; ++i)
        s += fmaxf(bf2f(z[(size_t)i * DIM + ch]) * a + c, 0.f);
    pooled[(size_t)g * DIM + ch] = s / fmaxf((float)(r1 - r0), 1.f);
}

// ---- head MLP ----
__global__ __launch_bounds__(128) void head_mlp(const float* __restrict__ pooled,
                                                const float* __restrict__ Wo1,
                                                const float* __restrict__ bo1,
                                                const float* __restrict__ Wo2,
                                                const float* __restrict__ bo2,
                                                float* __restrict__ out) {
    __shared__ float p[DIM];
    __shared__ float r0[128], r1[128];
    int g = blockIdx.x, j = threadIdx.x;
    for (int k = j; k < DIM; k += 128) p[k] = pooled[(size_t)g * DIM + k];
    __syncthreads();
    float acc = bo1[j];
    for (int k = 0; k < DIM; ++k) acc += p[k] * Wo1[k * 128 + j];
    float sp = (acc > 20.f) ? acc : log1pf(expf(acc));
    r0[j] = sp * Wo2[j * 2 + 0];
    r1[j] = sp * Wo2[j * 2 + 1];
    __syncthreads();
    for (int s = 64; s > 0; s >>= 1) {
        if (j < s) { r0[j] += r0[j + s]; r1[j] += r1[j + s]; }
        __syncthreads();
    }
    if (j == 0) {
        out[g * 2 + 0] = r0[0] + bo2[0];
        out[g * 2 + 1] = r1[0] + bo2[1];
    }
}

extern "C" void kernel_launch(void* const* d_in, const int* in_sizes, int n_in,
                              void* d_out, int out_size, void* d_ws, size_t ws_size,
                              hipStream_t stream) {
    (void)in_sizes; (void)n_in; (void)out_size;
    const int* x     = (const int*)d_in[0];
    const int* ei    = (const int*)d_in[1];
    const int* ea    = (const int*)d_in[2];
    const int* batch = (const int*)d_in[3];
    const float* xe1 = (const float*)d_in[4];
    const float* xe2 = (const float*)d_in[5];
    const float* ee1 = (const float*)d_in[6];
    const float* ee2 = (const float*)d_in[7];
    const float* W1  = (const float*)d_in[8];
    const float* b1  = (const float*)d_in[9];
    const float* W2  = (const float*)d_in[10];
    const float* b2  = (const float*)d_in[11];
    const float* bng = (const float*)d_in[12];
    const float* bnb = (const float*)d_in[13];
    const float* Wo1 = (const float*)d_in[14];
    const float* bo1 = (const float*)d_in[15];
    const float* Wo2 = (const float*)d_in[16];
    const float* bo2 = (const float*)d_in[17];
    float* out = (float*)d_out;

    if (ws_size < 112000000ull) return;   // need ~110 MB

    char* ws = (char*)d_ws;
    size_t off = 0;
    auto alloc = [&](size_t bytes) { void* p = ws + off; off += (bytes + 255) & ~255ull; return p; };
    unsigned short* z   = (unsigned short*)alloc((size_t)NNODES * DIM * 2);
    unsigned short* agg = (unsigned short*)alloc((size_t)NNODES * DIM * 2);
    unsigned short* Wt1 = (unsigned short*)alloc((size_t)NLAYERS * DIM * 2 * DIM * 2);
    unsigned short* Wt2 = (unsigned short*)alloc((size_t)NLAYERS * DIM * 2 * DIM * 2);
    float* etab         = (float*)alloc((size_t)NLAYERS * 15 * DIM * 4);
    float* stats        = (float*)alloc(2 * 512 * 4);          // ping-pong [2][512]
    float* pooled       = (float*)alloc((size_t)NB * DIM * 4);
    int* gstart         = (int*)alloc((size_t)(NB + 1) * 4);
    int* rowptr         = (int*)alloc((size_t)(NNODES + 1) * 4);
    int* deg            = (int*)alloc((size_t)NNODES * 4);
    int* esrc           = (int*)alloc((size_t)NEDGES * 4);
    int* eattr          = (int*)alloc((size_t)NEDGES * 4);
    int* bsum           = (int*)alloc((size_t)NSB * 4);

    const int WTOT = DIM * 2 * DIM;  // 131072

    transpose_w<<<dim3((WTOT + 255) / 256, NLAYERS), 256, 0, stream>>>(W1, Wt1, DIM, 2 * DIM);
    transpose_w<<<dim3((WTOT + 255) / 256, NLAYERS), 256, 0, stream>>>(W2, Wt2, 2 * DIM, DIM);
    build_etab<<<dim3(15, NLAYERS), DIM, 0, stream>>>(ee1, ee2, etab);

    zero_i32<<<(NNODES + 255) / 256, 256, 0, stream>>>(deg, NNODES);
    csr_hist<<<(NEDGES + 255) / 256, 256, 0, stream>>>(ei, deg);
    scan_blk<<<NSB, 1024, 0, stream>>>(deg, rowptr, bsum);
    scan_partials<<<1, 64, 0, stream>>>(bsum);
    scan_add<<<NSB, 1024, 0, stream>>>(rowptr, bsum);
    csr_fill<<<(NEDGES + 255) / 256, 256, 0, stream>>>(ei, ea, rowptr, deg, esrc, eattr);
    seg_starts<<<(NB + 1 + 255) / 256, 256, 0, stream>>>(batch, gstart);

    for (int l = 0; l < NLAYERS; ++l) {
        float* statsP = stats + ((l + 1) & 1) * 512;
        float* statsC = stats + (l & 1) * 512;
        if (l == 0)
            gather_k<0><<<NNODES / 4, 256, 0, stream>>>(z, x, xe1, xe2, statsP, bng, bnb, statsC,
                                                        etab, rowptr, esrc, eattr, agg);
        else
            gather_k<1><<<NNODES / 4, 256, 0, stream>>>(z, x, xe1, xe2, statsP,
                                                        bng + (size_t)(l - 1) * DIM, bnb + (size_t)(l - 1) * DIM,
                                                        statsC, etab + (size_t)l * 15 * DIM,
                                                        rowptr, esrc, eattr, agg);
        mlp64<<<(NNODES + 63) / 64, 512, 0, stream>>>(agg, Wt1 + (size_t)l * WTOT, b1 + l * 2 * DIM,
                                                      Wt2 + (size_t)l * WTOT, b2 + l * DIM, z, statsC);
    }

    pool_seg<<<NB, DIM, 0, stream>>>(z, stats + ((NLAYERS - 1) & 1) * 512,
                                     bng + (size_t)(NLAYERS - 1) * DIM, bnb + (size_t)(NLAYERS - 1) * DIM,
                                     gstart, pooled);
    head_mlp<<<NB, 128, 0, stream>>>(pooled, Wo1, bo1, Wo2, bo2, out);
}

// Round 11
// 1056.381 us; speedup vs baseline: 1.7400x; 1.0421x over previous
//
#include <hip/hip_runtime.h>

#define NNODES 100000
#define NEDGES 200000
#define NB     2048
#define DIM    256
#define NLAYERS 5
#define NSB    98   // ceil(100000/1024) scan blocks

typedef __bf16 bf16x8 __attribute__((ext_vector_type(8)));
typedef float  f32x4  __attribute__((ext_vector_type(4)));

__device__ __forceinline__ float bf2f(unsigned short u) {
    union { unsigned u; float f; } v; v.u = ((unsigned)u) << 16; return v.f;
}
__device__ __forceinline__ unsigned short f2bf(float f) {
    union { float f; unsigned u; } v; v.f = f;
    unsigned r = v.u + 0x7fff + ((v.u >> 16) & 1);   // RNE (finite values only)
    return (unsigned short)(r >> 16);
}
__device__ __forceinline__ float4 loadZ4(const unsigned short* z, size_t row, int ch) {
    ushort4 u = *(const ushort4*)&z[row * DIM + ch];
    float4 r; r.x = bf2f(u.x); r.y = bf2f(u.y); r.z = bf2f(u.z); r.w = bf2f(u.w); return r;
}

__global__ void zero_i32(int* __restrict__ p, int n) {
    int i = blockIdx.x * 256 + threadIdx.x;
    if (i < n) p[i] = 0;
}
__global__ void zero_f32(float* __restrict__ p, int n) {
    int i = blockIdx.x * 256 + threadIdx.x;
    if (i < n) p[i] = 0.f;
}

// ---- transpose+convert weights: W (L x K x Nw) fp32 -> Wt (L x Nw x K) bf16 ----
__global__ void transpose_w(const float* __restrict__ W,
                            unsigned short* __restrict__ Wt, int K, int Nw) {
    int l = blockIdx.y;
    int t = blockIdx.x * 256 + threadIdx.x;
    int total = K * Nw;
    if (t >= total) return;
    int k = t / Nw, n = t % Nw;
    Wt[(size_t)l * total + (size_t)n * K + k] = f2bf(W[(size_t)l * total + t]);
}

// ---- edge-embedding table ----
__global__ void build_etab(const float* __restrict__ ee1, const float* __restrict__ ee2,
                           float* __restrict__ etab) {
    int l = blockIdx.y, c = blockIdx.x, d = threadIdx.x;   // c in [0,15)
    etab[((size_t)l * 15 + c) * DIM + d] =
        ee1[((size_t)l * 5 + c / 3) * DIM + d] + ee2[((size_t)l * 3 + c % 3) * DIM + d];
}

// ---- CSR build ----
__global__ void csr_hist(const int* __restrict__ ei, int* __restrict__ deg) {
    int j = blockIdx.x * 256 + threadIdx.x;
    if (j < NEDGES) atomicAdd(&deg[ei[NEDGES + j]], 1);
}
__global__ __launch_bounds__(1024) void scan_blk(const int* __restrict__ deg,
                                                 int* __restrict__ rowptr,
                                                 int* __restrict__ bsum) {
    __shared__ int s[1024];
    int b = blockIdx.x, t = threadIdx.x, i = b * 1024 + t;
    s[t] = (i < NNODES) ? deg[i] : 0;
    __syncthreads();
    #pragma unroll
    for (int off = 1; off < 1024; off <<= 1) {
        int u = (t >= off) ? s[t - off] : 0;
        __syncthreads();
        s[t] += u;
        __syncthreads();
    }
    if (i < NNODES) rowptr[i + 1] = s[t];
    if (t == 1023) bsum[b] = s[1023];
}
__global__ void scan_partials(int* __restrict__ bsum) {
    if (threadIdx.x == 0) {
        int acc = 0;
        for (int k = 0; k < NSB; ++k) { acc += bsum[k]; bsum[k] = acc; }
    }
}
__global__ void scan_add(int* __restrict__ rowptr, const int* __restrict__ bsum) {
    int b = blockIdx.x, t = threadIdx.x, i = b * 1024 + t;
    if (b > 0 && i < NNODES) rowptr[i + 1] += bsum[b - 1];
    if (b == 0 && t == 0) rowptr[0] = 0;
}
__global__ void csr_fill(const int* __restrict__ ei, const int* __restrict__ ea,
                         const int* __restrict__ rowptr, int* __restrict__ deg,
                         int* __restrict__ esrc, int* __restrict__ eattr) {
    int j = blockIdx.x * 256 + threadIdx.x;
    if (j >= NEDGES) return;
    int d = ei[NEDGES + j];
    int pos = atomicSub(&deg[d], 1) - 1;
    int slot = rowptr[d] + pos;
    esrc[slot] = ei[j];
    eattr[slot] = ea[2 * j] * 3 + ea[2 * j + 1];
}

// ---- segment starts ----
__global__ void seg_starts(const int* __restrict__ batch, int* __restrict__ start) {
    int g = blockIdx.x * 256 + threadIdx.x;
    if (g > NB) return;
    int lo = 0, hi = NNODES;
    while (lo < hi) { int mid = (lo + hi) >> 1; if (batch[mid] < g) lo = mid + 1; else hi = mid; }
    start[g] = lo;
}

// ---- fused layer: gather (CSR + BN + edge-emb) -> LDS -> 2-GEMM MLP -> zdst + stats ----
// MODE 0: h = xe1[x0]+xe2[x1] (layer 0). MODE 1: h = relu(zsrc*a+c), BN inline from statsP.
// 64 rows/block, 8 waves; wave w gathers rows w*8+[0,8); quarter-split GEMM (r10 body).
// Block 0 zeroes statsZ (layer l+1's stats buffer; safe: its readers finished last dispatch).
template <int MODE>
__global__ __launch_bounds__(512, 6) void layer_k(const unsigned short* __restrict__ zsrc,
                                                  unsigned short* __restrict__ zdst,
                                                  const int* __restrict__ x,
                                                  const float* __restrict__ xe1,
                                                  const float* __restrict__ xe2,
                                                  const float* __restrict__ statsP,
                                                  float* __restrict__ statsZ,
                                                  const float* __restrict__ g_,
                                                  const float* __restrict__ b_,
                                                  const float* __restrict__ etab_l,
                                                  const int* __restrict__ rowptr,
                                                  const int* __restrict__ esrc,
                                                  const int* __restrict__ eattr,
                                                  const unsigned short* __restrict__ Wt1,
                                                  const float* __restrict__ b1,
                                                  const unsigned short* __restrict__ Wt2,
                                                  const float* __restrict__ b2,
                                                  float* __restrict__ stats) {
    __shared__ unsigned short As[64 * 264];   // 33792 B
    __shared__ unsigned short Ts[64 * 136];   // 17408 B (one t-quarter)

    const int rowBase = blockIdx.x * 64;
    const int tid = threadIdx.x;
    const int lane = tid & 63, w = tid >> 6;
    const int lrow = lane & 15, lq = lane >> 4;

    if (blockIdx.x == 0 && tid < 512) statsZ[tid] = 0.f;

    // ---- stage A: fused gather into As ----
    {
        const int ch = lane * 4;
        float4 a4, c4;
        if (MODE == 1) {
            float4 s4 = *(const float4*)&statsP[ch];
            float4 q4 = *(const float4*)&statsP[256 + ch];
            float4 g4 = *(const float4*)&g_[ch];
            float4 b4 = *(const float4*)&b_[ch];
            const float invN = 1.0f / (float)NNODES;
            float mux = s4.x * invN, muy = s4.y * invN, muz = s4.z * invN, muw = s4.w * invN;
            a4.x = g4.x * rsqrtf(q4.x * invN - mux * mux + 1e-5f);
            a4.y = g4.y * rsqrtf(q4.y * invN - muy * muy + 1e-5f);
            a4.z = g4.z * rsqrtf(q4.z * invN - muz * muz + 1e-5f);
            a4.w = g4.w * rsqrtf(q4.w * invN - muw * muw + 1e-5f);
            c4.x = b4.x - mux * a4.x; c4.y = b4.y - muy * a4.y;
            c4.z = b4.z - muz * a4.z; c4.w = b4.w - muw * a4.w;
        }
        auto hrow = [&](int row) -> float4 {
            if (MODE == 0) {
                int i0 = x[2 * row], i1 = x[2 * row + 1];
                float4 u = *(const float4*)&xe1[(size_t)i0 * DIM + ch];
                float4 v = *(const float4*)&xe2[(size_t)i1 * DIM + ch];
                return make_float4(u.x + v.x, u.y + v.y, u.z + v.z, u.w + v.w);
            } else {
                float4 h = loadZ4(zsrc, (size_t)row, ch);
                h.x = fmaxf(h.x * a4.x + c4.x, 0.f); h.y = fmaxf(h.y * a4.y + c4.y, 0.f);
                h.z = fmaxf(h.z * a4.z + c4.z, 0.f); h.w = fmaxf(h.w * a4.w + c4.w, 0.f);
                return h;
            }
        };
        float4 se = *(const float4*)&etab_l[12 * DIM + ch];   // self edge (bt=4,bd=0)
        #pragma unroll
        for (int r8 = 0; r8 < 8; ++r8) {
            int row = rowBase + w * 8 + r8;
            float4 acc = make_float4(0.f, 0.f, 0.f, 0.f);
            if (row < NNODES) {
                float4 hv = hrow(row);
                acc = make_float4(hv.x + se.x, hv.y + se.y, hv.z + se.z, hv.w + se.w);
                int r0 = rowptr[row], r1 = rowptr[row + 1];
                int e = r0;
                for (; e + 2 <= r1; e += 2) {
                    int s0 = esrc[e], c0 = eattr[e];
                    int s1 = esrc[e + 1], c1 = eattr[e + 1];
                    float4 h0 = hrow(s0);
                    float4 h1 = hrow(s1);
                    float4 e0 = *(const float4*)&etab_l[c0 * DIM + ch];
                    float4 e1 = *(const float4*)&etab_l[c1 * DIM + ch];
                    acc.x += h0.x + e0.x + h1.x + e1.x; acc.y += h0.y + e0.y + h1.y + e1.y;
                    acc.z += h0.z + e0.z + h1.z + e1.z; acc.w += h0.w + e0.w + h1.w + e1.w;
                }
                if (e < r1) {
                    int s0 = esrc[e], c0 = eattr[e];
                    float4 h0 = hrow(s0);
                    float4 e0 = *(const float4*)&etab_l[c0 * DIM + ch];
                    acc.x += h0.x + e0.x; acc.y += h0.y + e0.y;
                    acc.z += h0.z + e0.z; acc.w += h0.w + e0.w;
                }
            }
            ushort4 o; o.x = f2bf(acc.x); o.y = f2bf(acc.y); o.z = f2bf(acc.z); o.w = f2bf(acc.w);
            *(ushort4*)&As[(w * 8 + r8) * 264 + ch] = o;
        }
    }
    f32x4 acc2[4][2]{};
    __syncthreads();

    // ---- quarter-split GEMM (r10 body) ----
    #pragma unroll
    for (int q = 0; q < 4; ++q) {
        f32x4 acc1[4]{};
        const unsigned short* w1p = &Wt1[(size_t)(q * 128 + w * 16 + lrow) * DIM];
        #pragma unroll
        for (int kk = 0; kk < 8; ++kk) {
            const int kc = kk * 32 + lq * 8;
            bf16x8 b = *(const bf16x8*)&w1p[kc];
            bf16x8 a[4];
            #pragma unroll
            for (int mi = 0; mi < 4; ++mi)
                a[mi] = *(const bf16x8*)&As[(mi * 16 + lrow) * 264 + kc];
            #pragma unroll
            for (int mi = 0; mi < 4; ++mi)
                acc1[mi] = __builtin_amdgcn_mfma_f32_16x16x32_bf16(a[mi], b, acc1[mi], 0, 0, 0);
        }
        if (q > 0) __syncthreads();
        {
            int col = w * 16 + lrow;
            float bv = b1[q * 128 + col];
            #pragma unroll
            for (int mi = 0; mi < 4; ++mi)
                #pragma unroll
                for (int r = 0; r < 4; ++r)
                    Ts[(mi * 16 + lq * 4 + r) * 136 + col] = f2bf(fmaxf(acc1[mi][r] + bv, 0.f));
        }
        __syncthreads();
        #pragma unroll
        for (int kk = 0; kk < 4; ++kk) {
            const int kc = kk * 32 + lq * 8;
            bf16x8 a[4], b[2];
            #pragma unroll
            for (int mi = 0; mi < 4; ++mi)
                a[mi] = *(const bf16x8*)&Ts[(mi * 16 + lrow) * 136 + kc];
            #pragma unroll
            for (int ni = 0; ni < 2; ++ni)
                b[ni] = *(const bf16x8*)&Wt2[(size_t)(w * 32 + ni * 16 + lrow) * (2 * DIM) + q * 128 + kc];
            #pragma unroll
            for (int mi = 0; mi < 4; ++mi)
                #pragma unroll
                for (int ni = 0; ni < 2; ++ni)
                    acc2[mi][ni] = __builtin_amdgcn_mfma_f32_16x16x32_bf16(a[mi], b[ni], acc2[mi][ni], 0, 0, 0);
        }
    }

    // ---- epilogue: zdst store + stats atomics ----
    #pragma unroll
    for (int ni = 0; ni < 2; ++ni) {
        int col = w * 32 + ni * 16 + lrow;
        float bv = b2[col];
        float s = 0.f, q = 0.f;
        #pragma unroll
        for (int mi = 0; mi < 4; ++mi)
            #pragma unroll
            for (int r = 0; r < 4; ++r) {
                int row = rowBase + mi * 16 + lq * 4 + r;
                if (row < NNODES) {
                    float v = acc2[mi][ni][r] + bv;
                    zdst[(size_t)row * DIM + col] = f2bf(v);
                    s += v; q += v * v;
                }
            }
        s += __shfl_xor(s, 16); s += __shfl_xor(s, 32);
        q += __shfl_xor(q, 16); q += __shfl_xor(q, 32);
        if (lq == 0) {
            atomicAdd(&stats[col], s);
            atomicAdd(&stats[DIM + col], q);
        }
    }
}

// ---- pooled[g] = mean(relu(z*a+c)) over sorted segment; BN inline from stats ----
__global__ __launch_bounds__(256) void pool_seg(const unsigned short* __restrict__ z,
                                                const float* __restrict__ statsP,
                                                const float* __restrict__ g_,
                                                const float* __restrict__ b_,
                                                const int* __restrict__ start,
                                                float* __restrict__ pooled) {
    int g = blockIdx.x, ch = threadIdx.x;
    float mu = statsP[ch] / (float)NNODES;
    float var = statsP[256 + ch] / (float)NNODES - mu * mu;
    float a = g_[ch] * rsqrtf(var + 1e-5f);
    float c = b_[ch] - mu * a;
    int r0 = start[g], r1 = start[g + 1];
    float s = 0.f;
    for (int i = r0; i < r1; ++i)
        s += fmaxf(bf2f(z[(size_t)i * DIM + ch]) * a + c, 0.f);
    pooled[(size_t)g * DIM + ch] = s / fmaxf((float)(r1 - r0), 1.f);
}

// ---- head MLP ----
__global__ __launch_bounds__(128) void head_mlp(const float* __restrict__ pooled,
                                                const float* __restrict__ Wo1,
                                                const float* __restrict__ bo1,
                                                const float* __restrict__ Wo2,
                                                const float* __restrict__ bo2,
                                                float* __restrict__ out) {
    __shared__ float p[DIM];
    __shared__ float r0[128], r1[128];
    int g = blockIdx.x, j = threadIdx.x;
    for (int k = j; k < DIM; k += 128) p[k] = pooled[(size_t)g * DIM + k];
    __syncthreads();
    float acc = bo1[j];
    for (int k = 0; k < DIM; ++k) acc += p[k] * Wo1[k * 128 + j];
    float sp = (acc > 20.f) ? acc : log1pf(expf(acc));
    r0[j] = sp * Wo2[j * 2 + 0];
    r1[j] = sp * Wo2[j * 2 + 1];
    __syncthreads();
    for (int s = 64; s > 0; s >>= 1) {
        if (j < s) { r0[j] += r0[j + s]; r1[j] += r1[j + s]; }
        __syncthreads();
    }
    if (j == 0) {
        out[g * 2 + 0] = r0[0] + bo2[0];
        out[g * 2 + 1] = r1[0] + bo2[1];
    }
}

extern "C" void kernel_launch(void* const* d_in, const int* in_sizes, int n_in,
                              void* d_out, int out_size, void* d_ws, size_t ws_size,
                              hipStream_t stream) {
    (void)in_sizes; (void)n_in; (void)out_size;
    const int* x     = (const int*)d_in[0];
    const int* ei    = (const int*)d_in[1];
    const int* ea    = (const int*)d_in[2];
    const int* batch = (const int*)d_in[3];
    const float* xe1 = (const float*)d_in[4];
    const float* xe2 = (const float*)d_in[5];
    const float* ee1 = (const float*)d_in[6];
    const float* ee2 = (const float*)d_in[7];
    const float* W1  = (const float*)d_in[8];
    const float* b1  = (const float*)d_in[9];
    const float* W2  = (const float*)d_in[10];
    const float* b2  = (const float*)d_in[11];
    const float* bng = (const float*)d_in[12];
    const float* bnb = (const float*)d_in[13];
    const float* Wo1 = (const float*)d_in[14];
    const float* bo1 = (const float*)d_in[15];
    const float* Wo2 = (const float*)d_in[16];
    const float* bo2 = (const float*)d_in[17];
    float* out = (float*)d_out;

    if (ws_size < 112000000ull) return;   // need ~109 MB

    char* ws = (char*)d_ws;
    size_t off = 0;
    auto alloc = [&](size_t bytes) { void* p = ws + off; off += (bytes + 255) & ~255ull; return p; };
    unsigned short* zA  = (unsigned short*)alloc((size_t)NNODES * DIM * 2);
    unsigned short* zB  = (unsigned short*)alloc((size_t)NNODES * DIM * 2);
    unsigned short* Wt1 = (unsigned short*)alloc((size_t)NLAYERS * DIM * 2 * DIM * 2);
    unsigned short* Wt2 = (unsigned short*)alloc((size_t)NLAYERS * DIM * 2 * DIM * 2);
    float* etab         = (float*)alloc((size_t)NLAYERS * 15 * DIM * 4);
    float* stats        = (float*)alloc(3 * 512 * 4);          // 3-rotation [3][512]
    float* pooled       = (float*)alloc((size_t)NB * DIM * 4);
    int* gstart         = (int*)alloc((size_t)(NB + 1) * 4);
    int* rowptr         = (int*)alloc((size_t)(NNODES + 1) * 4);
    int* deg            = (int*)alloc((size_t)NNODES * 4);
    int* esrc           = (int*)alloc((size_t)NEDGES * 4);
    int* eattr          = (int*)alloc((size_t)NEDGES * 4);
    int* bsum           = (int*)alloc((size_t)NSB * 4);

    const int WTOT = DIM * 2 * DIM;  // 131072
    unsigned short* zb[2] = { zA, zB };

    transpose_w<<<dim3((WTOT + 255) / 256, NLAYERS), 256, 0, stream>>>(W1, Wt1, DIM, 2 * DIM);
    transpose_w<<<dim3((WTOT + 255) / 256, NLAYERS), 256, 0, stream>>>(W2, Wt2, 2 * DIM, DIM);
    build_etab<<<dim3(15, NLAYERS), DIM, 0, stream>>>(ee1, ee2, etab);
    zero_f32<<<2, 256, 0, stream>>>(stats, 512);   // layer 0's stats buffer

    zero_i32<<<(NNODES + 255) / 256, 256, 0, stream>>>(deg, NNODES);
    csr_hist<<<(NEDGES + 255) / 256, 256, 0, stream>>>(ei, deg);
    scan_blk<<<NSB, 1024, 0, stream>>>(deg, rowptr, bsum);
    scan_partials<<<1, 64, 0, stream>>>(bsum);
    scan_add<<<NSB, 1024, 0, stream>>>(rowptr, bsum);
    csr_fill<<<(NEDGES + 255) / 256, 256, 0, stream>>>(ei, ea, rowptr, deg, esrc, eattr);
    seg_starts<<<(NB + 1 + 255) / 256, 256, 0, stream>>>(batch, gstart);

    const int NBLK = (NNODES + 63) / 64;
    for (int l = 0; l < NLAYERS; ++l) {
        float* statsC = stats + (size_t)(l % 3) * 512;
        float* statsP = stats + (size_t)((l + 2) % 3) * 512;
        float* statsZ = stats + (size_t)((l + 1) % 3) * 512;
        if (l == 0)
            layer_k<0><<<NBLK, 512, 0, stream>>>(zb[0], zb[1], x, xe1, xe2, statsP, statsZ,
                                                 bng, bnb, etab, rowptr, esrc, eattr,
                                                 Wt1, b1, Wt2, b2, statsC);
        else
            layer_k<1><<<NBLK, 512, 0, stream>>>(zb[l & 1], zb[(l + 1) & 1], x, xe1, xe2, statsP, statsZ,
                                                 bng + (size_t)(l - 1) * DIM, bnb + (size_t)(l - 1) * DIM,
                                                 etab + (size_t)l * 15 * DIM, rowptr, esrc, eattr,
                                                 Wt1 + (size_t)l * WTOT, b1 + (size_t)l * 2 * DIM,
                                                 Wt2 + (size_t)l * WTOT, b2 + (size_t)l * DIM, statsC);
    }

    pool_seg<<<NB, DIM, 0, stream>>>(zb[NLAYERS & 1], stats + (size_t)((NLAYERS - 1) % 3) * 512,
                                     bng + (size_t)(NLAYERS - 1) * DIM, bnb + (size_t)(NLAYERS - 1) * DIM,
                                     gstart, pooled);
    head_mlp<<<NB, 128, 0, stream>>>(pooled, Wo1, bo1, Wo2, bo2, out);
}